// Round 5
// baseline (475.370 us; speedup 1.0000x reference)
//
#include <hip/hip_runtime.h>
#include <hip/hip_bf16.h>
#include <math.h>

#define TSEQ 2048
#define BATCH 2
#define CDIM 1024
#define NH 16
#define HD 64
#define DFF 4096
#define ROWS (BATCH*TSEQ)   // 4096

typedef __attribute__((ext_vector_type(4))) float f32x4;
typedef __attribute__((ext_vector_type(8))) short bf16x8;   // 8 bf16 in 4 VGPRs
typedef __attribute__((ext_vector_type(4))) unsigned short u16x4;

__device__ __forceinline__ void gload_lds16(const void* g, void* l) {
    void* gv = const_cast<void*>(g);
    __builtin_amdgcn_global_load_lds((__attribute__((address_space(1))) void*)gv,
                                     (__attribute__((address_space(3))) void*)l, 16, 0, 0);
}

__device__ __forceinline__ unsigned short f2bf(float f) {
    unsigned int u = __float_as_uint(f);
    return (unsigned short)((u + 0x7FFFu + ((u >> 16) & 1u)) >> 16);
}

// ------------------------------- LayerNorm -> bf16 --------------------------------
__global__ __launch_bounds__(256) void ln_kernel(const float* __restrict__ x,
                                                 const float* __restrict__ g,
                                                 const float* __restrict__ b,
                                                 unsigned short* __restrict__ out) {
    int row = blockIdx.x;
    int tid = threadIdx.x;
    const float* xr = x + (size_t)row * CDIM;
    float4 v = *(const float4*)(xr + tid * 4);
    float s  = v.x + v.y + v.z + v.w;
    float s2 = v.x*v.x + v.y*v.y + v.z*v.z + v.w*v.w;
    #pragma unroll
    for (int off = 32; off >= 1; off >>= 1) {
        s  += __shfl_down(s, off);
        s2 += __shfl_down(s2, off);
    }
    __shared__ float red[8];
    int wid = tid >> 6, lane = tid & 63;
    if (lane == 0) { red[wid] = s; red[wid + 4] = s2; }
    __syncthreads();
    float ts  = red[0] + red[1] + red[2] + red[3];
    float ts2 = red[4] + red[5] + red[6] + red[7];
    float mu  = ts * (1.0f / CDIM);
    float var = ts2 * (1.0f / CDIM) - mu * mu;
    float rstd = rsqrtf(var + 1e-5f);
    float4 gv = *(const float4*)(g + tid * 4);
    float4 bv = *(const float4*)(b + tid * 4);
    unsigned short o4[4];
    o4[0] = f2bf((v.x - mu) * rstd * gv.x + bv.x);
    o4[1] = f2bf((v.y - mu) * rstd * gv.y + bv.y);
    o4[2] = f2bf((v.z - mu) * rstd * gv.z + bv.z);
    o4[3] = f2bf((v.w - mu) * rstd * gv.w + bv.w);
    *(u16x4*)(out + (size_t)row * CDIM + tid * 4) = *(u16x4*)o4;
}

// --------------------- transpose + cast: W[K][N] f32 -> Wt[N][K] bf16 ---------------
__global__ __launch_bounds__(256) void transpose_cast_kernel(const float* __restrict__ W,
                                                             unsigned short* __restrict__ Wt,
                                                             int K, int N) {
    __shared__ float T[64][65];
    int tid = threadIdx.x;
    int n0 = blockIdx.x * 64, k0 = blockIdx.y * 64;
    int kr = tid >> 4;
    int nc = (tid & 15) * 4;
    #pragma unroll
    for (int i = 0; i < 4; ++i) {
        float4 v = *(const float4*)&W[(size_t)(k0 + kr + i*16) * N + (n0 + nc)];
        T[kr + i*16][nc + 0] = v.x;
        T[kr + i*16][nc + 1] = v.y;
        T[kr + i*16][nc + 2] = v.z;
        T[kr + i*16][nc + 3] = v.w;
    }
    __syncthreads();
    int n  = tid >> 2;
    int kb = (tid & 3) * 16;
    unsigned short tmp[16];
    #pragma unroll
    for (int i = 0; i < 16; ++i) tmp[i] = f2bf(T[kb + i][n]);
    unsigned short* dst = Wt + (size_t)(n0 + n) * K + (k0 + kb);
    *(int4*)dst       = *(int4*)&tmp[0];
    *(int4*)(dst + 8) = *(int4*)&tmp[8];
}

// ------------- V transpose: qkv V-part -> VtG[b][h][d][s] (bf16) -------------------
// grid (TSEQ/64, BATCH*NH), block 256.
__global__ __launch_bounds__(256) void vtrans_kernel(const unsigned short* __restrict__ qkv,
                                                     unsigned short* __restrict__ vtg) {
    __shared__ unsigned short T[64][72];
    const int tid = threadIdx.x;
    const int st  = blockIdx.x;            // s-tile
    const int bh  = blockIdx.y;
    const int b   = bh >> 4, h = bh & 15;
    {
        const int sl = tid >> 2;           // 0..63
        const int dc = (tid & 3) * 16;
        const unsigned short* src = qkv + ((size_t)(b * TSEQ + st * 64 + sl)) * 3072 + 2048 + h * 64 + dc;
        bf16x8 v0 = *(const bf16x8*)src;
        bf16x8 v1 = *(const bf16x8*)(src + 8);
        #pragma unroll
        for (int i = 0; i < 8; ++i) {
            T[sl][dc + i]     = (unsigned short)v0[i];
            T[sl][dc + 8 + i] = (unsigned short)v1[i];
        }
    }
    __syncthreads();
    {
        const int d  = tid >> 2;           // 0..63
        const int sc = (tid & 3) * 16;
        unsigned short tmp[16];
        #pragma unroll
        for (int i = 0; i < 16; ++i) tmp[i] = T[sc + i][d];
        unsigned short* dst = vtg + (((size_t)(b * NH + h) * 64 + d) * TSEQ) + st * 64 + sc;
        *(int4*)dst       = *(int4*)&tmp[0];
        *(int4*)(dst + 8) = *(int4*)&tmp[8];
    }
}

// ---------------- MFMA GEMM (TN): C[M,N] = A[M,K](bf16) @ Bt[N,K](bf16)^T ----------
// EPI: 0 = bias -> bf16 out; 1 = bias + f32 residual -> f32 out; 2 = bias+GELU -> bf16 out
template<int EPI>
__global__ __launch_bounds__(256) void gemm_kernel(const unsigned short* __restrict__ A,
                                                   const unsigned short* __restrict__ Bt,
                                                   const float* __restrict__ bias,
                                                   const float* __restrict__ res,
                                                   void* __restrict__ Cout,
                                                   int M, int N, int K) {
    __shared__ __align__(16) unsigned short As[128 * 32];
    __shared__ __align__(16) unsigned short Bs[128 * 32];
    const int tid = threadIdx.x;
    const int l   = tid & 63;
    const int w   = tid >> 6;
    const int wr  = (w >> 1) * 64;
    const int wc  = (w & 1) * 64;
    const long brow = (long)blockIdx.y * 128;
    const long bcol = (long)blockIdx.x * 128;

    const unsigned short* gA0 = A  + (size_t)(brow + (tid >> 2)) * K + (tid & 3) * 8;
    const unsigned short* gA1 = gA0 + (size_t)64 * K;
    const unsigned short* gB0 = Bt + (size_t)(bcol + (tid >> 2)) * K + (tid & 3) * 8;
    const unsigned short* gB1 = gB0 + (size_t)64 * K;
    unsigned short* lA0 = As + tid * 8;
    unsigned short* lA1 = As + 2048 + tid * 8;
    unsigned short* lB0 = Bs + tid * 8;
    unsigned short* lB1 = Bs + 2048 + tid * 8;

    f32x4 acc[4][4];
    #pragma unroll
    for (int m = 0; m < 4; ++m)
        #pragma unroll
        for (int n = 0; n < 4; ++n) acc[m][n] = (f32x4){0.f, 0.f, 0.f, 0.f};

    const int aoff = (wr + (l & 15)) * 32 + (l >> 4) * 8;
    const int boff = (wc + (l & 15)) * 32 + (l >> 4) * 8;

    for (int k0 = 0; k0 < K; k0 += 32) {
        gload_lds16(gA0 + k0, lA0);
        gload_lds16(gA1 + k0, lA1);
        gload_lds16(gB0 + k0, lB0);
        gload_lds16(gB1 + k0, lB1);
        __syncthreads();
        bf16x8 af[4], bf[4];
        #pragma unroll
        for (int m = 0; m < 4; ++m) af[m] = *(const bf16x8*)&As[aoff + m * 512];
        #pragma unroll
        for (int n = 0; n < 4; ++n) bf[n] = *(const bf16x8*)&Bs[boff + n * 512];
        #pragma unroll
        for (int m = 0; m < 4; ++m)
            #pragma unroll
            for (int n = 0; n < 4; ++n)
                acc[m][n] = __builtin_amdgcn_mfma_f32_16x16x32_bf16(af[m], bf[n], acc[m][n], 0, 0, 0);
        __syncthreads();
    }

    #pragma unroll
    for (int m = 0; m < 4; ++m) {
        const int rown = wr + m * 16 + (l >> 4) * 4;
        #pragma unroll
        for (int n = 0; n < 4; ++n) {
            const long col = bcol + wc + n * 16 + (l & 15);
            const float bb = bias[col];
            #pragma unroll
            for (int r = 0; r < 4; ++r) {
                const long row = brow + rown + r;
                float v = acc[m][n][r] + bb;
                if (EPI == 1) {
                    v += res[row * N + col];
                    ((float*)Cout)[row * N + col] = v;
                } else if (EPI == 2) {
                    v = 0.5f * v * (1.0f + erff(v * 0.70710678118f));
                    ((unsigned short*)Cout)[row * N + col] = f2bf(v);
                } else {
                    ((unsigned short*)Cout)[row * N + col] = f2bf(v);
                }
            }
        }
    }
}

// ------------------- MFMA causal flash attention (barrier-free) --------------------
// K frags read directly from qkv (L2-resident per head); V frags from pre-transposed
// VtG[b][h][d][s]. No __syncthreads in the KV loop; Ps is wave-private (lgkm-ordered).
// 1-D grid 1024 (= 2 b x 16 h x 32 qi): head->XCD swizzle, longest-qi first.
__global__ __launch_bounds__(256, 4) void attn_kernel(const unsigned short* __restrict__ qkv,
                                                      const unsigned short* __restrict__ vtg,
                                                      unsigned short* __restrict__ out) {
    __shared__ __align__(16) unsigned short Ps[64 * 64];   // [q][s], chunk-XOR swizzled, wave-private rows

    const int tid = threadIdx.x;
    const int l   = tid & 63;
    const int w   = tid >> 6;
    const int lin = blockIdx.x;
    const int b    = lin >> 9;                 // 512 blocks per batch
    const int r9   = lin & 511;
    const int xcd  = r9 & 7;
    const int slot = r9 >> 3;                  // 0..63
    const int h    = xcd + 8 * (slot & 1);     // head pair {xcd, xcd+8} pinned to one XCD
    const int qi   = 31 - (slot >> 1);         // longest first
    const size_t rowbase = (size_t)b * TSEQ;

    const unsigned short* kbase = qkv + rowbase * 3072 + 1024 + h * 64;     // + s*3072 + d
    const unsigned short* vbase = vtg + ((size_t)(b * NH + h) * 64) * TSEQ; // + d*TSEQ + s

    // hoisted Q fragments (A operand, rows l&15 of this wave's 16 q-rows)
    bf16x8 aq0, aq1;
    {
        const int qrow = qi * 64 + w * 16 + (l & 15);
        const unsigned short* qp = qkv + (rowbase + qrow) * 3072 + h * 64 + (l >> 4) * 8;
        aq0 = *(const bf16x8*)qp;
        aq1 = *(const bf16x8*)(qp + 32);
    }

    float mrow[4], lrow[4];
    #pragma unroll
    for (int r = 0; r < 4; ++r) { mrow[r] = -INFINITY; lrow[r] = 0.f; }
    f32x4 o[4];
    #pragma unroll
    for (int d = 0; d < 4; ++d) o[d] = (f32x4){0.f, 0.f, 0.f, 0.f};

    for (int j = 0; j <= qi; ++j) {
        // ---- K fragments: B[k=d][n=s], lane: s = sb*16 + (l&15), d = (l>>4)*8 (+32) ----
        bf16x8 kf0[4], kf1[4];
        #pragma unroll
        for (int sb = 0; sb < 4; ++sb) {
            const unsigned short* kp = kbase + (size_t)(j * 64 + sb * 16 + (l & 15)) * 3072 + (l >> 4) * 8;
            kf0[sb] = *(const bf16x8*)kp;
            kf1[sb] = *(const bf16x8*)(kp + 32);
        }
        // ---- V fragments: B[k=s][n=d], lane: d = db*16 + (l&15), s = j*64 + kb*32 + (l>>4)*8
        bf16x8 vf[2][4];
        #pragma unroll
        for (int kb = 0; kb < 2; ++kb)
            #pragma unroll
            for (int db = 0; db < 4; ++db)
                vf[kb][db] = *(const bf16x8*)(vbase + (size_t)(db * 16 + (l & 15)) * TSEQ
                                              + j * 64 + kb * 32 + (l >> 4) * 8);

        // ---- S = Q K^T ----
        f32x4 sf[4];
        __builtin_amdgcn_s_setprio(1);
        #pragma unroll
        for (int sb = 0; sb < 4; ++sb) {
            sf[sb] = (f32x4){0.f, 0.f, 0.f, 0.f};
            sf[sb] = __builtin_amdgcn_mfma_f32_16x16x32_bf16(aq0, kf0[sb], sf[sb], 0, 0, 0);
            sf[sb] = __builtin_amdgcn_mfma_f32_16x16x32_bf16(aq1, kf1[sb], sf[sb], 0, 0, 0);
        }
        __builtin_amdgcn_s_setprio(0);

        // scale + causal mask (diagonal tile only)
        #pragma unroll
        for (int sb = 0; sb < 4; ++sb)
            #pragma unroll
            for (int r = 0; r < 4; ++r) sf[sb][r] *= 0.125f;
        if (j == qi) {
            const int qrl = w * 16 + (l >> 4) * 4;
            #pragma unroll
            for (int sb = 0; sb < 4; ++sb) {
                const int scol = sb * 16 + (l & 15);
                #pragma unroll
                for (int r = 0; r < 4; ++r)
                    if (scol > qrl + r) sf[sb][r] = -INFINITY;
            }
        }

        // online softmax: row r lives in lanes sharing (l>>4); reduce across low 4 lane bits
        float mnew[4], alpha[4], psum[4];
        #pragma unroll
        for (int r = 0; r < 4; ++r) {
            float mx = fmaxf(fmaxf(sf[0][r], sf[1][r]), fmaxf(sf[2][r], sf[3][r]));
            mx = fmaxf(mx, __shfl_xor(mx, 1));
            mx = fmaxf(mx, __shfl_xor(mx, 2));
            mx = fmaxf(mx, __shfl_xor(mx, 4));
            mx = fmaxf(mx, __shfl_xor(mx, 8));
            float mn = fmaxf(mrow[r], mx);
            mnew[r]  = mn;
            alpha[r] = __expf(mrow[r] - mn);
            mrow[r]  = mn;
        }
        #pragma unroll
        for (int r = 0; r < 4; ++r) psum[r] = 0.f;
        #pragma unroll
        for (int sb = 0; sb < 4; ++sb) {
            const int scol = sb * 16 + (l & 15);
            #pragma unroll
            for (int r = 0; r < 4; ++r) {
                float p = __expf(sf[sb][r] - mnew[r]);
                psum[r] += p;
                const int prow = w * 16 + (l >> 4) * 4 + r;
                Ps[prow * 64 + (((scol >> 3) ^ (prow & 7)) * 8) + (scol & 7)] = f2bf(p);
            }
        }
        #pragma unroll
        for (int r = 0; r < 4; ++r) {
            float ps = psum[r];
            ps += __shfl_xor(ps, 1);
            ps += __shfl_xor(ps, 2);
            ps += __shfl_xor(ps, 4);
            ps += __shfl_xor(ps, 8);
            lrow[r] = lrow[r] * alpha[r] + ps;
            #pragma unroll
            for (int d = 0; d < 4; ++d) o[d][r] *= alpha[r];
        }

        // ---- O += P V (Ps rows wave-private; compiler orders via lgkmcnt) ----
        __builtin_amdgcn_s_setprio(1);
        #pragma unroll
        for (int kb = 0; kb < 2; ++kb) {
            const int prow = w * 16 + (l & 15);
            bf16x8 pa = *(const bf16x8*)&Ps[prow * 64 + ((kb * 4 + (l >> 4)) ^ (prow & 7)) * 8];
            #pragma unroll
            for (int db = 0; db < 4; ++db)
                o[db] = __builtin_amdgcn_mfma_f32_16x16x32_bf16(pa, vf[kb][db], o[db], 0, 0, 0);
        }
        __builtin_amdgcn_s_setprio(0);
    }

    // epilogue: O / l -> bf16
    const int orow = qi * 64 + w * 16 + (l >> 4) * 4;
    #pragma unroll
    for (int r = 0; r < 4; ++r) {
        const float inv = 1.0f / lrow[r];
        const size_t rb = (rowbase + orow + r) * (size_t)CDIM + h * 64 + (l & 15);
        #pragma unroll
        for (int d = 0; d < 4; ++d)
            out[rb + d * 16] = f2bf(o[d][r] * inv);
    }
}

extern "C" void kernel_launch(void* const* d_in, const int* in_sizes, int n_in,
                              void* d_out, int out_size, void* d_ws, size_t ws_size,
                              hipStream_t stream) {
    const float* x     = (const float*)d_in[0];
    const float* ln1_g = (const float*)d_in[1];
    const float* ln1_b = (const float*)d_in[2];
    const float* w_qkv = (const float*)d_in[3];
    const float* b_qkv = (const float*)d_in[4];
    const float* w_out = (const float*)d_in[5];
    const float* b_out = (const float*)d_in[6];
    const float* ln2_g = (const float*)d_in[7];
    const float* ln2_b = (const float*)d_in[8];
    const float* w_ff1 = (const float*)d_in[9];
    const float* b_ff1 = (const float*)d_in[10];
    const float* w_ff2 = (const float*)d_in[11];
    const float* b_ff2 = (const float*)d_in[12];
    float* out = (float*)d_out;

    char* wsb = (char*)d_ws;
    unsigned short* h_bf    = (unsigned short*)(wsb);                          // 8 MB
    unsigned short* qkv_bf  = (unsigned short*)(wsb + 8ll  * 1024 * 1024);     // 24 MB
    unsigned short* attn_bf = (unsigned short*)(wsb + 32ll * 1024 * 1024);     // 8 MB
    float*          x1      = (float*)         (wsb + 40ll * 1024 * 1024);     // 16 MB
    unsigned short* vtg     = (unsigned short*)(wsb + 40ll * 1024 * 1024);     // 8 MB, overlays x1 (dead until step 4)
    unsigned short* wqkvT   = (unsigned short*)(wsb + 56ll * 1024 * 1024);     // 6 MB
    unsigned short* woutT   = (unsigned short*)(wsb + 62ll * 1024 * 1024);     // 2 MB
    unsigned short* wff1T   = (unsigned short*)(wsb + 64ll * 1024 * 1024);     // 8 MB
    unsigned short* wff2T   = (unsigned short*)(wsb + 72ll * 1024 * 1024);     // 8 MB
    unsigned short* ff1_bf  = (unsigned short*)(wsb + 8ll  * 1024 * 1024);     // 32 MB, overlays dead qkv+attn

    transpose_cast_kernel<<<dim3(48, 16), 256, 0, stream>>>(w_qkv, wqkvT, 1024, 3072);
    transpose_cast_kernel<<<dim3(16, 16), 256, 0, stream>>>(w_out, woutT, 1024, 1024);
    transpose_cast_kernel<<<dim3(64, 16), 256, 0, stream>>>(w_ff1, wff1T, 1024, 4096);
    transpose_cast_kernel<<<dim3(16, 64), 256, 0, stream>>>(w_ff2, wff2T, 4096, 1024);

    // 1. LN1 -> bf16
    ln_kernel<<<ROWS, 256, 0, stream>>>(x, ln1_g, ln1_b, h_bf);
    // 2. qkv = h @ w_qkv + b  -> bf16
    gemm_kernel<0><<<dim3(24, 32), 256, 0, stream>>>(h_bf, wqkvT, b_qkv, nullptr, qkv_bf, ROWS, 3072, 1024);
    // 2b. V transpose -> VtG[b][h][d][s]
    vtrans_kernel<<<dim3(32, 32), 256, 0, stream>>>(qkv_bf, vtg);
    // 3. causal flash attention -> bf16
    attn_kernel<<<1024, 256, 0, stream>>>(qkv_bf, vtg, attn_bf);
    // 4. x1 = x + attn @ w_out + b  -> f32   (overwrites vtg region; vtg is dead)
    gemm_kernel<1><<<dim3(8, 32), 256, 0, stream>>>(attn_bf, woutT, b_out, x, x1, ROWS, 1024, 1024);
    // 5. LN2 -> bf16
    ln_kernel<<<ROWS, 256, 0, stream>>>(x1, ln2_g, ln2_b, h_bf);
    // 6. ff1 = gelu(h @ w_ff1 + b)  -> bf16
    gemm_kernel<2><<<dim3(32, 32), 256, 0, stream>>>(h_bf, wff1T, b_ff1, nullptr, ff1_bf, ROWS, 4096, 1024);
    // 7. out = x1 + ff1 @ w_ff2 + b  -> f32
    gemm_kernel<1><<<dim3(8, 32), 256, 0, stream>>>(ff1_bf, wff2T, b_ff2, x1, (float*)out, ROWS, 1024, 4096);
}

// Round 6
// 383.739 us; speedup vs baseline: 1.2388x; 1.2388x over previous
//
#include <hip/hip_runtime.h>
#include <hip/hip_bf16.h>
#include <math.h>

#define TSEQ 2048
#define BATCH 2
#define CDIM 1024
#define NH 16
#define HD 64
#define DFF 4096
#define ROWS (BATCH*TSEQ)   // 4096

typedef __attribute__((ext_vector_type(4))) float f32x4;
typedef __attribute__((ext_vector_type(8))) short bf16x8;   // 8 bf16 in 4 VGPRs
typedef __attribute__((ext_vector_type(4))) unsigned short u16x4;

__device__ __forceinline__ void gload_lds16(const void* g, void* l) {
    void* gv = const_cast<void*>(g);
    __builtin_amdgcn_global_load_lds((__attribute__((address_space(1))) void*)gv,
                                     (__attribute__((address_space(3))) void*)l, 16, 0, 0);
}

__device__ __forceinline__ unsigned short f2bf(float f) {
    unsigned int u = __float_as_uint(f);
    return (unsigned short)((u + 0x7FFFu + ((u >> 16) & 1u)) >> 16);
}

// ------------------------------- LayerNorm -> bf16 --------------------------------
__global__ __launch_bounds__(256) void ln_kernel(const float* __restrict__ x,
                                                 const float* __restrict__ g,
                                                 const float* __restrict__ b,
                                                 unsigned short* __restrict__ out) {
    int row = blockIdx.x;
    int tid = threadIdx.x;
    const float* xr = x + (size_t)row * CDIM;
    float4 v = *(const float4*)(xr + tid * 4);
    float s  = v.x + v.y + v.z + v.w;
    float s2 = v.x*v.x + v.y*v.y + v.z*v.z + v.w*v.w;
    #pragma unroll
    for (int off = 32; off >= 1; off >>= 1) {
        s  += __shfl_down(s, off);
        s2 += __shfl_down(s2, off);
    }
    __shared__ float red[8];
    int wid = tid >> 6, lane = tid & 63;
    if (lane == 0) { red[wid] = s; red[wid + 4] = s2; }
    __syncthreads();
    float ts  = red[0] + red[1] + red[2] + red[3];
    float ts2 = red[4] + red[5] + red[6] + red[7];
    float mu  = ts * (1.0f / CDIM);
    float var = ts2 * (1.0f / CDIM) - mu * mu;
    float rstd = rsqrtf(var + 1e-5f);
    float4 gv = *(const float4*)(g + tid * 4);
    float4 bv = *(const float4*)(b + tid * 4);
    unsigned short o4[4];
    o4[0] = f2bf((v.x - mu) * rstd * gv.x + bv.x);
    o4[1] = f2bf((v.y - mu) * rstd * gv.y + bv.y);
    o4[2] = f2bf((v.z - mu) * rstd * gv.z + bv.z);
    o4[3] = f2bf((v.w - mu) * rstd * gv.w + bv.w);
    *(u16x4*)(out + (size_t)row * CDIM + tid * 4) = *(u16x4*)o4;
}

// --------------------- transpose + cast: W[K][N] f32 -> Wt[N][K] bf16 ---------------
__global__ __launch_bounds__(256) void transpose_cast_kernel(const float* __restrict__ W,
                                                             unsigned short* __restrict__ Wt,
                                                             int K, int N) {
    __shared__ float T[64][65];
    int tid = threadIdx.x;
    int n0 = blockIdx.x * 64, k0 = blockIdx.y * 64;
    int kr = tid >> 4;
    int nc = (tid & 15) * 4;
    #pragma unroll
    for (int i = 0; i < 4; ++i) {
        float4 v = *(const float4*)&W[(size_t)(k0 + kr + i*16) * N + (n0 + nc)];
        T[kr + i*16][nc + 0] = v.x;
        T[kr + i*16][nc + 1] = v.y;
        T[kr + i*16][nc + 2] = v.z;
        T[kr + i*16][nc + 3] = v.w;
    }
    __syncthreads();
    int n  = tid >> 2;
    int kb = (tid & 3) * 16;
    unsigned short tmp[16];
    #pragma unroll
    for (int i = 0; i < 16; ++i) tmp[i] = f2bf(T[kb + i][n]);
    unsigned short* dst = Wt + (size_t)(n0 + n) * K + (k0 + kb);
    *(int4*)dst       = *(int4*)&tmp[0];
    *(int4*)(dst + 8) = *(int4*)&tmp[8];
}

// ------------- V transpose: qkv V-part -> VtG[b][h][d][s] (bf16) -------------------
// grid (TSEQ/64, BATCH*NH), block 256.
__global__ __launch_bounds__(256) void vtrans_kernel(const unsigned short* __restrict__ qkv,
                                                     unsigned short* __restrict__ vtg) {
    __shared__ unsigned short T[64][72];
    const int tid = threadIdx.x;
    const int st  = blockIdx.x;            // s-tile
    const int bh  = blockIdx.y;
    const int b   = bh >> 4, h = bh & 15;
    {
        const int sl = tid >> 2;           // 0..63
        const int dc = (tid & 3) * 16;
        const unsigned short* src = qkv + ((size_t)(b * TSEQ + st * 64 + sl)) * 3072 + 2048 + h * 64 + dc;
        bf16x8 v0 = *(const bf16x8*)src;
        bf16x8 v1 = *(const bf16x8*)(src + 8);
        #pragma unroll
        for (int i = 0; i < 8; ++i) {
            T[sl][dc + i]     = (unsigned short)v0[i];
            T[sl][dc + 8 + i] = (unsigned short)v1[i];
        }
    }
    __syncthreads();
    {
        const int d  = tid >> 2;           // 0..63
        const int sc = (tid & 3) * 16;
        unsigned short tmp[16];
        #pragma unroll
        for (int i = 0; i < 16; ++i) tmp[i] = T[sc + i][d];
        unsigned short* dst = vtg + (((size_t)(b * NH + h) * 64 + d) * TSEQ) + st * 64 + sc;
        *(int4*)dst       = *(int4*)&tmp[0];
        *(int4*)(dst + 8) = *(int4*)&tmp[8];
    }
}

// ---------------- MFMA GEMM (TN): C[M,N] = A[M,K](bf16) @ Bt[N,K](bf16)^T ----------
// EPI: 0 = bias -> bf16 out; 1 = bias + f32 residual -> f32 out; 2 = bias+GELU -> bf16 out
template<int EPI>
__global__ __launch_bounds__(256) void gemm_kernel(const unsigned short* __restrict__ A,
                                                   const unsigned short* __restrict__ Bt,
                                                   const float* __restrict__ bias,
                                                   const float* __restrict__ res,
                                                   void* __restrict__ Cout,
                                                   int M, int N, int K) {
    __shared__ __align__(16) unsigned short As[128 * 32];
    __shared__ __align__(16) unsigned short Bs[128 * 32];
    const int tid = threadIdx.x;
    const int l   = tid & 63;
    const int w   = tid >> 6;
    const int wr  = (w >> 1) * 64;
    const int wc  = (w & 1) * 64;
    const long brow = (long)blockIdx.y * 128;
    const long bcol = (long)blockIdx.x * 128;

    const unsigned short* gA0 = A  + (size_t)(brow + (tid >> 2)) * K + (tid & 3) * 8;
    const unsigned short* gA1 = gA0 + (size_t)64 * K;
    const unsigned short* gB0 = Bt + (size_t)(bcol + (tid >> 2)) * K + (tid & 3) * 8;
    const unsigned short* gB1 = gB0 + (size_t)64 * K;
    unsigned short* lA0 = As + tid * 8;
    unsigned short* lA1 = As + 2048 + tid * 8;
    unsigned short* lB0 = Bs + tid * 8;
    unsigned short* lB1 = Bs + 2048 + tid * 8;

    f32x4 acc[4][4];
    #pragma unroll
    for (int m = 0; m < 4; ++m)
        #pragma unroll
        for (int n = 0; n < 4; ++n) acc[m][n] = (f32x4){0.f, 0.f, 0.f, 0.f};

    const int aoff = (wr + (l & 15)) * 32 + (l >> 4) * 8;
    const int boff = (wc + (l & 15)) * 32 + (l >> 4) * 8;

    for (int k0 = 0; k0 < K; k0 += 32) {
        gload_lds16(gA0 + k0, lA0);
        gload_lds16(gA1 + k0, lA1);
        gload_lds16(gB0 + k0, lB0);
        gload_lds16(gB1 + k0, lB1);
        __syncthreads();
        bf16x8 af[4], bf[4];
        #pragma unroll
        for (int m = 0; m < 4; ++m) af[m] = *(const bf16x8*)&As[aoff + m * 512];
        #pragma unroll
        for (int n = 0; n < 4; ++n) bf[n] = *(const bf16x8*)&Bs[boff + n * 512];
        #pragma unroll
        for (int m = 0; m < 4; ++m)
            #pragma unroll
            for (int n = 0; n < 4; ++n)
                acc[m][n] = __builtin_amdgcn_mfma_f32_16x16x32_bf16(af[m], bf[n], acc[m][n], 0, 0, 0);
        __syncthreads();
    }

    #pragma unroll
    for (int m = 0; m < 4; ++m) {
        const int rown = wr + m * 16 + (l >> 4) * 4;
        #pragma unroll
        for (int n = 0; n < 4; ++n) {
            const long col = bcol + wc + n * 16 + (l & 15);
            const float bb = bias[col];
            #pragma unroll
            for (int r = 0; r < 4; ++r) {
                const long row = brow + rown + r;
                float v = acc[m][n][r] + bb;
                if (EPI == 1) {
                    v += res[row * N + col];
                    ((float*)Cout)[row * N + col] = v;
                } else if (EPI == 2) {
                    v = 0.5f * v * (1.0f + erff(v * 0.70710678118f));
                    ((unsigned short*)Cout)[row * N + col] = f2bf(v);
                } else {
                    ((unsigned short*)Cout)[row * N + col] = f2bf(v);
                }
            }
        }
    }
}

// ------------------- MFMA causal flash attention (barrier-free) --------------------
// K frags from qkv (L2-resident per head); V frags from VtG[b][h][d][s]. No
// __syncthreads in the KV loop; Ps is wave-private. Each block processes TWO q-tiles
// (p and 31-p) -> uniform 33 tile-steps/block. Grid 512 = 2b x 8xcd x (2h x 16pairs).
// V frags loaded AFTER QK^T so they reuse K-frag registers (peak VGPR ~100, no spill).
__global__ __launch_bounds__(256) void attn_kernel(const unsigned short* __restrict__ qkv,
                                                   const unsigned short* __restrict__ vtg,
                                                   unsigned short* __restrict__ out) {
    __shared__ __align__(16) unsigned short Ps[64 * 64];   // [q][s], chunk-XOR swizzled, wave-private rows

    const int tid = threadIdx.x;
    const int l   = tid & 63;
    const int w   = tid >> 6;
    const int lin = blockIdx.x;
    const int b    = lin >> 8;                 // 256 blocks per batch
    const int r8   = lin & 255;
    const int xcd  = r8 & 7;
    const int slot = r8 >> 3;                  // 0..31
    const int h    = xcd + 8 * (slot & 1);     // head pair {xcd, xcd+8} pinned to one XCD
    const int pair = slot >> 1;                // 0..15
    const size_t rowbase = (size_t)b * TSEQ;

    const unsigned short* kbase = qkv + rowbase * 3072 + 1024 + h * 64;     // + s*3072 + d
    const unsigned short* vbase = vtg + ((size_t)(b * NH + h) * 64) * TSEQ; // + d*TSEQ + s

    for (int t = 0; t < 2; ++t) {
        const int qi = t == 0 ? (31 - pair) : pair;   // long tile first

        // hoisted Q fragments (A operand, rows l&15 of this wave's 16 q-rows)
        bf16x8 aq0, aq1;
        {
            const int qrow = qi * 64 + w * 16 + (l & 15);
            const unsigned short* qp = qkv + (rowbase + qrow) * 3072 + h * 64 + (l >> 4) * 8;
            aq0 = *(const bf16x8*)qp;
            aq1 = *(const bf16x8*)(qp + 32);
        }

        float mrow[4], lrow[4];
        #pragma unroll
        for (int r = 0; r < 4; ++r) { mrow[r] = -INFINITY; lrow[r] = 0.f; }
        f32x4 o[4];
        #pragma unroll
        for (int d = 0; d < 4; ++d) o[d] = (f32x4){0.f, 0.f, 0.f, 0.f};

        for (int j = 0; j <= qi; ++j) {
            // ---- K fragments: B[k=d][n=s], lane: s = sb*16 + (l&15), d = (l>>4)*8 (+32)
            bf16x8 kf0[4], kf1[4];
            #pragma unroll
            for (int sb = 0; sb < 4; ++sb) {
                const unsigned short* kp = kbase + (size_t)(j * 64 + sb * 16 + (l & 15)) * 3072 + (l >> 4) * 8;
                kf0[sb] = *(const bf16x8*)kp;
                kf1[sb] = *(const bf16x8*)(kp + 32);
            }

            // ---- S = Q K^T ----
            f32x4 sf[4];
            __builtin_amdgcn_s_setprio(1);
            #pragma unroll
            for (int sb = 0; sb < 4; ++sb) {
                sf[sb] = (f32x4){0.f, 0.f, 0.f, 0.f};
                sf[sb] = __builtin_amdgcn_mfma_f32_16x16x32_bf16(aq0, kf0[sb], sf[sb], 0, 0, 0);
                sf[sb] = __builtin_amdgcn_mfma_f32_16x16x32_bf16(aq1, kf1[sb], sf[sb], 0, 0, 0);
            }
            __builtin_amdgcn_s_setprio(0);

            // ---- V fragments (kf regs now dead -> reuse; softmax VALU covers latency)
            // lane: d = db*16 + (l&15), s = j*64 + kb*32 + (l>>4)*8
            bf16x8 vf[2][4];
            #pragma unroll
            for (int kb = 0; kb < 2; ++kb)
                #pragma unroll
                for (int db = 0; db < 4; ++db)
                    vf[kb][db] = *(const bf16x8*)(vbase + (size_t)(db * 16 + (l & 15)) * TSEQ
                                                  + j * 64 + kb * 32 + (l >> 4) * 8);

            // scale + causal mask (diagonal tile only)
            #pragma unroll
            for (int sb = 0; sb < 4; ++sb)
                #pragma unroll
                for (int r = 0; r < 4; ++r) sf[sb][r] *= 0.125f;
            if (j == qi) {
                const int qrl = w * 16 + (l >> 4) * 4;
                #pragma unroll
                for (int sb = 0; sb < 4; ++sb) {
                    const int scol = sb * 16 + (l & 15);
                    #pragma unroll
                    for (int r = 0; r < 4; ++r)
                        if (scol > qrl + r) sf[sb][r] = -INFINITY;
                }
            }

            // online softmax: row r lives in lanes sharing (l>>4); reduce across low 4 lane bits
            float mnew[4], alpha[4], psum[4];
            #pragma unroll
            for (int r = 0; r < 4; ++r) {
                float mx = fmaxf(fmaxf(sf[0][r], sf[1][r]), fmaxf(sf[2][r], sf[3][r]));
                mx = fmaxf(mx, __shfl_xor(mx, 1));
                mx = fmaxf(mx, __shfl_xor(mx, 2));
                mx = fmaxf(mx, __shfl_xor(mx, 4));
                mx = fmaxf(mx, __shfl_xor(mx, 8));
                float mn = fmaxf(mrow[r], mx);
                mnew[r]  = mn;
                alpha[r] = __expf(mrow[r] - mn);
                mrow[r]  = mn;
            }
            #pragma unroll
            for (int r = 0; r < 4; ++r) psum[r] = 0.f;
            #pragma unroll
            for (int sb = 0; sb < 4; ++sb) {
                const int scol = sb * 16 + (l & 15);
                #pragma unroll
                for (int r = 0; r < 4; ++r) {
                    float p = __expf(sf[sb][r] - mnew[r]);
                    psum[r] += p;
                    const int prow = w * 16 + (l >> 4) * 4 + r;
                    Ps[prow * 64 + (((scol >> 3) ^ (prow & 7)) * 8) + (scol & 7)] = f2bf(p);
                }
            }
            #pragma unroll
            for (int r = 0; r < 4; ++r) {
                float ps = psum[r];
                ps += __shfl_xor(ps, 1);
                ps += __shfl_xor(ps, 2);
                ps += __shfl_xor(ps, 4);
                ps += __shfl_xor(ps, 8);
                lrow[r] = lrow[r] * alpha[r] + ps;
                #pragma unroll
                for (int d = 0; d < 4; ++d) o[d][r] *= alpha[r];
            }

            // ---- O += P V (Ps rows wave-private; compiler orders via lgkmcnt) ----
            __builtin_amdgcn_s_setprio(1);
            #pragma unroll
            for (int kb = 0; kb < 2; ++kb) {
                const int prow = w * 16 + (l & 15);
                bf16x8 pa = *(const bf16x8*)&Ps[prow * 64 + ((kb * 4 + (l >> 4)) ^ (prow & 7)) * 8];
                #pragma unroll
                for (int db = 0; db < 4; ++db)
                    o[db] = __builtin_amdgcn_mfma_f32_16x16x32_bf16(pa, vf[kb][db], o[db], 0, 0, 0);
            }
            __builtin_amdgcn_s_setprio(0);
        }

        // epilogue: O / l -> bf16
        const int orow = qi * 64 + w * 16 + (l >> 4) * 4;
        #pragma unroll
        for (int r = 0; r < 4; ++r) {
            const float inv = 1.0f / lrow[r];
            const size_t rb = (rowbase + orow + r) * (size_t)CDIM + h * 64 + (l & 15);
            #pragma unroll
            for (int d = 0; d < 4; ++d)
                out[rb + d * 16] = f2bf(o[d][r] * inv);
        }
    }
}

extern "C" void kernel_launch(void* const* d_in, const int* in_sizes, int n_in,
                              void* d_out, int out_size, void* d_ws, size_t ws_size,
                              hipStream_t stream) {
    const float* x     = (const float*)d_in[0];
    const float* ln1_g = (const float*)d_in[1];
    const float* ln1_b = (const float*)d_in[2];
    const float* w_qkv = (const float*)d_in[3];
    const float* b_qkv = (const float*)d_in[4];
    const float* w_out = (const float*)d_in[5];
    const float* b_out = (const float*)d_in[6];
    const float* ln2_g = (const float*)d_in[7];
    const float* ln2_b = (const float*)d_in[8];
    const float* w_ff1 = (const float*)d_in[9];
    const float* b_ff1 = (const float*)d_in[10];
    const float* w_ff2 = (const float*)d_in[11];
    const float* b_ff2 = (const float*)d_in[12];
    float* out = (float*)d_out;

    char* wsb = (char*)d_ws;
    unsigned short* h_bf    = (unsigned short*)(wsb);                          // 8 MB
    unsigned short* qkv_bf  = (unsigned short*)(wsb + 8ll  * 1024 * 1024);     // 24 MB
    unsigned short* attn_bf = (unsigned short*)(wsb + 32ll * 1024 * 1024);     // 8 MB
    float*          x1      = (float*)         (wsb + 40ll * 1024 * 1024);     // 16 MB
    unsigned short* vtg     = (unsigned short*)(wsb + 40ll * 1024 * 1024);     // 8 MB, overlays x1 (dead until step 4)
    unsigned short* wqkvT   = (unsigned short*)(wsb + 56ll * 1024 * 1024);     // 6 MB
    unsigned short* woutT   = (unsigned short*)(wsb + 62ll * 1024 * 1024);     // 2 MB
    unsigned short* wff1T   = (unsigned short*)(wsb + 64ll * 1024 * 1024);     // 8 MB
    unsigned short* wff2T   = (unsigned short*)(wsb + 72ll * 1024 * 1024);     // 8 MB
    unsigned short* ff1_bf  = (unsigned short*)(wsb + 8ll  * 1024 * 1024);     // 32 MB, overlays dead qkv+attn

    transpose_cast_kernel<<<dim3(48, 16), 256, 0, stream>>>(w_qkv, wqkvT, 1024, 3072);
    transpose_cast_kernel<<<dim3(16, 16), 256, 0, stream>>>(w_out, woutT, 1024, 1024);
    transpose_cast_kernel<<<dim3(64, 16), 256, 0, stream>>>(w_ff1, wff1T, 1024, 4096);
    transpose_cast_kernel<<<dim3(16, 64), 256, 0, stream>>>(w_ff2, wff2T, 4096, 1024);

    // 1. LN1 -> bf16
    ln_kernel<<<ROWS, 256, 0, stream>>>(x, ln1_g, ln1_b, h_bf);
    // 2. qkv = h @ w_qkv + b  -> bf16
    gemm_kernel<0><<<dim3(24, 32), 256, 0, stream>>>(h_bf, wqkvT, b_qkv, nullptr, qkv_bf, ROWS, 3072, 1024);
    // 2b. V transpose -> VtG[b][h][d][s]
    vtrans_kernel<<<dim3(32, 32), 256, 0, stream>>>(qkv_bf, vtg);
    // 3. causal flash attention -> bf16 (512 uniform blocks: q-tile pairs)
    attn_kernel<<<512, 256, 0, stream>>>(qkv_bf, vtg, attn_bf);
    // 4. x1 = x + attn @ w_out + b  -> f32   (overwrites vtg region; vtg is dead)
    gemm_kernel<1><<<dim3(8, 32), 256, 0, stream>>>(attn_bf, woutT, b_out, x, x1, ROWS, 1024, 1024);
    // 5. LN2 -> bf16
    ln_kernel<<<ROWS, 256, 0, stream>>>(x1, ln2_g, ln2_b, h_bf);
    // 6. ff1 = gelu(h @ w_ff1 + b)  -> bf16
    gemm_kernel<2><<<dim3(32, 32), 256, 0, stream>>>(h_bf, wff1T, b_ff1, nullptr, ff1_bf, ROWS, 4096, 1024);
    // 7. out = x1 + ff1 @ w_ff2 + b  -> f32
    gemm_kernel<1><<<dim3(8, 32), 256, 0, stream>>>(ff1_bf, wff2T, b_ff2, x1, (float*)out, ROWS, 1024, 4096);
}